// Round 8
// baseline (78.080 us; speedup 1.0000x reference)
//
#include <hip/hip_runtime.h>

// ============================================================================
// ROUND 8 = TANH-KERNEL MEASUREMENT ROUND. tanh kernel reverted to the R5
// trans form (+ wt staged in LDS), inner loop run REP=4 (accumulate, scale
// 0.25 at the end — exact & deterministic) so the kernel exceeds the ~40us
// fillBuffer rows and surfaces in rocprof top-5 with real counters.
// ============================================================================

#define BB 16
#define TV 256
#define TS 32
#define DD 512

typedef float    floatx4  __attribute__((ext_vector_type(4)));
typedef short    short8   __attribute__((ext_vector_type(8)));
typedef unsigned short ushort8 __attribute__((ext_vector_type(8)));

#define TANH_SCALE 2.885390082f   // 2*log2(e): tanh(y)=1-2/(exp2(2y*log2e)+1)

static __device__ __forceinline__ unsigned short f2bf(float f) {
    unsigned int u = __float_as_uint(f);
    u += 0x7FFFu + ((u >> 16) & 1u);   // RNE (inputs finite)
    return (unsigned short)(u >> 16);
}

// ---------------------------------------------------------------------------
// Pass 1: convert video/sent/w1/w2 f32 -> bf16 once (memory-bound, ~26 MB).
// ---------------------------------------------------------------------------
__global__ __launch_bounds__(256) void ta_convert(
    const float* __restrict__ video, const float* __restrict__ sent,
    const float* __restrict__ w1,    const float* __restrict__ w2,
    unsigned short* __restrict__ vb, unsigned short* __restrict__ sb,
    unsigned short* __restrict__ w1b, unsigned short* __restrict__ w2b)
{
    const int NV = BB * TV * DD, NS = BB * TS * DD, NW = DD * DD;
    const int base = (blockIdx.x * 256 + threadIdx.x) * 8;
    const float* src; unsigned short* dst; int off;
    if      (base < NV)           { src = video; dst = vb;  off = base; }
    else if (base < NV + NS)      { src = sent;  dst = sb;  off = base - NV; }
    else if (base < NV + NS + NW) { src = w1;    dst = w1b; off = base - NV - NS; }
    else                          { src = w2;    dst = w2b; off = base - NV - NS - NW; }
    const float4 a = *(const float4*)(src + off);
    const float4 b = *(const float4*)(src + off + 4);
    ushort8 o;
    o[0] = f2bf(a.x); o[1] = f2bf(a.y); o[2] = f2bf(a.z); o[3] = f2bf(a.w);
    o[4] = f2bf(b.x); o[5] = f2bf(b.y); o[6] = f2bf(b.z); o[7] = f2bf(b.w);
    *(ushort8*)(dst + off) = o;
}

// ---------------------------------------------------------------------------
// Pass 2: merged bf16-MFMA NT GEMM (measured ~2.5us total, unchanged from R5).
// ---------------------------------------------------------------------------
__global__ __launch_bounds__(256) void ta_mfma_gemm(
    const unsigned short* __restrict__ vb, const unsigned short* __restrict__ w1b,
    const float* __restrict__ b1,          const float* __restrict__ vmask,
    float* __restrict__ tmp1,
    const unsigned short* __restrict__ sb, const unsigned short* __restrict__ w2b,
    const float* __restrict__ smask,       unsigned short* __restrict__ tmp2,
    const float* __restrict__ wt,          float* __restrict__ wsum)
{
    const int t = threadIdx.x;

    if (blockIdx.x == 0 && t < 64) {
        float v = 0.f;
        for (int i = t; i < DD; i += 64) v += wt[i];
        for (int off = 32; off; off >>= 1) v += __shfl_down(v, off);
        if (t == 0) wsum[0] = v;
    }

    const bool g2 = (blockIdx.x >= 512);
    const int bid = g2 ? (int)blockIdx.x - 512 : (int)blockIdx.x;
    const unsigned short* __restrict__ A = g2 ? sb    : vb;
    const unsigned short* __restrict__ W = g2 ? w2b   : w1b;
    const float* __restrict__ rm         = g2 ? smask : vmask;
    const int m0 = (g2 ? (bid & 7)  : (bid & 63)) * 64;
    const int n0 = (g2 ? (bid >> 3) : (bid >> 6)) * 64;

    __shared__ unsigned short As[2][4096];
    __shared__ unsigned short Bs[2][4096];

    const int lane = t & 63;
    const int wid  = t >> 6;
    const int wm   = wid >> 1, wn = wid & 1;
    const int lr   = lane & 15, kg = lane >> 4;

    const int r0 = t >> 3,          g0c = (t & 7) ^ (r0 & 7);
    const int r1 = (t + 256) >> 3,  g1c = (t & 7) ^ (r1 & 7);
    const unsigned short* a0p = A + (size_t)(m0 + r0) * DD + g0c * 8;
    const unsigned short* a1p = A + (size_t)(m0 + r1) * DD + g1c * 8;
    const unsigned short* w0p = W + (size_t)(n0 + r0) * DD + g0c * 8;
    const unsigned short* w1p = W + (size_t)(n0 + r1) * DD + g1c * 8;
    const int l0 = t * 8;
    const int l1 = (t + 256) * 8;

#define TA_STAGE(buf, koff) do {                                               \
    __builtin_amdgcn_global_load_lds(                                          \
        (const __attribute__((address_space(1))) void*)(a0p + (koff)),         \
        (__attribute__((address_space(3))) void*)&As[buf][l0], 16, 0, 0);      \
    __builtin_amdgcn_global_load_lds(                                          \
        (const __attribute__((address_space(1))) void*)(a1p + (koff)),         \
        (__attribute__((address_space(3))) void*)&As[buf][l1], 16, 0, 0);      \
    __builtin_amdgcn_global_load_lds(                                          \
        (const __attribute__((address_space(1))) void*)(w0p + (koff)),         \
        (__attribute__((address_space(3))) void*)&Bs[buf][l0], 16, 0, 0);      \
    __builtin_amdgcn_global_load_lds(                                          \
        (const __attribute__((address_space(1))) void*)(w1p + (koff)),         \
        (__attribute__((address_space(3))) void*)&Bs[buf][l1], 16, 0, 0);      \
  } while (0)

    floatx4 acc[2][2] = {};

    const int ml0 = wm * 32 + lr, ml1 = ml0 + 16;
    const int nl0 = wn * 32 + lr, nl1 = nl0 + 16;
    const int sa0 = ml0 * 64, sa1 = ml1 * 64;
    const int sb0 = nl0 * 64, sb1 = nl1 * 64;
    const int xa = ml0 & 7, xb = nl0 & 7;

    TA_STAGE(0, 0);
    __syncthreads();

    int cur = 0;
    for (int step = 0; step < 8; ++step) {
        if (step < 7) TA_STAGE(cur ^ 1, (step + 1) * 64);
#pragma unroll
        for (int kk = 0; kk < 2; ++kk) {
            const int kc = kk * 4 + kg;
            short8 a0 = *(const short8*)&As[cur][sa0 + ((kc ^ xa) << 3)];
            short8 a1 = *(const short8*)&As[cur][sa1 + ((kc ^ xa) << 3)];
            short8 b0 = *(const short8*)&Bs[cur][sb0 + ((kc ^ xb) << 3)];
            short8 b1 = *(const short8*)&Bs[cur][sb1 + ((kc ^ xb) << 3)];
            acc[0][0] = __builtin_amdgcn_mfma_f32_16x16x32_bf16(a0, b0, acc[0][0], 0, 0, 0);
            acc[0][1] = __builtin_amdgcn_mfma_f32_16x16x32_bf16(a0, b1, acc[0][1], 0, 0, 0);
            acc[1][0] = __builtin_amdgcn_mfma_f32_16x16x32_bf16(a1, b0, acc[1][0], 0, 0, 0);
            acc[1][1] = __builtin_amdgcn_mfma_f32_16x16x32_bf16(a1, b1, acc[1][1], 0, 0, 0);
        }
        __syncthreads();
        cur ^= 1;
    }
#undef TA_STAGE

#pragma unroll
    for (int fm = 0; fm < 2; ++fm)
#pragma unroll
        for (int fn = 0; fn < 2; ++fn)
#pragma unroll
            for (int r = 0; r < 4; ++r) {
                const int m = m0 + wm * 32 + fm * 16 + kg * 4 + r;
                const int n = n0 + wn * 32 + fn * 16 + lr;
                const float mk = rm[m] * TANH_SCALE;
                const float val = acc[fm][fn][r];
                if (!g2) tmp1[(size_t)m * DD + n] = (val + b1[n]) * mk;
                else     tmp2[(size_t)m * DD + n] = f2bf(val * mk);
            }
}

// ---------------------------------------------------------------------------
// Pass 3: fused pairwise tanh reduction (R5 trans form + wt-in-LDS),
// REP=4 measurement loop. out = pm*(wsum - 0.5*acc4)  [acc4 = 4x true sum].
// Block = 512 threads = 4 v x 32 s x 4 d-quarters; grid = 1024.
// LDS: t2s 32KB + wts 2KB + part 2KB = 36KB.
// ---------------------------------------------------------------------------
__global__ __launch_bounds__(512) void ta_tanh_main(
    const float* __restrict__ tmp1,          // [B*TV][D] f32, prescaled
    const unsigned short* __restrict__ tmp2, // [B*TS][D] bf16, prescaled
    const float* __restrict__ wt,            // [D]
    const float* __restrict__ wsum,          // [1]
    const float* __restrict__ vmask,         // [B*TV]
    const float* __restrict__ smask,         // [B*TS]
    float* __restrict__ out)                 // [B][TV][TS]
{
    __shared__ unsigned short t2s[TS * DD];  // 32 KB
    __shared__ float wts[DD];                // 2 KB
    __shared__ float part[512];              // 2 KB

    const int t  = threadIdx.x;
    const int b  = blockIdx.x >> 6;
    const int v0 = (blockIdx.x & 63) << 2;

    {
        const unsigned short* src = tmp2 + (size_t)b * TS * DD;
#pragma unroll
        for (int i = 0; i < 4; ++i) {
            const int chunk = t + 512 * i;
            const int row = chunk >> 6;
            const int c   = chunk & 63;
            ushort8 val = *(const ushort8*)&src[chunk * 8];
            *(ushort8*)&t2s[row * DD + ((c ^ (row & 15)) << 3)] = val;
        }
        if (t < DD / 4) ((float4*)wts)[t] = ((const float4*)wt)[t];
    }
    __syncthreads();

    const int s  = t & 31;
    const int vi = (t >> 5) & 3;
    const int q  = __builtin_amdgcn_readfirstlane(t >> 7);
    const int v  = v0 + vi;

    const float pm = vmask[b * TV + v] * smask[b * TS + s];
    const float* __restrict__ x1p = tmp1 + ((size_t)(b * TV + v)) * DD + q * 128;
    const float* __restrict__ wtl = wts + q * 128;   // LDS, wave-uniform addr
    const int rowbase = s * DD;
    const int swz = s & 15;

    floatx4 acc4a = {0.f, 0.f, 0.f, 0.f};
    floatx4 acc4b = {0.f, 0.f, 0.f, 0.f};
#pragma unroll 1
    for (int rep = 0; rep < 4; ++rep) {   // MEASUREMENT: 4x same work
#pragma unroll 2
        for (int i = 0; i < 16; ++i) {
            uint4 u4 = *(const uint4*)&t2s[rowbase + (((q * 16 + i) ^ swz) << 3)];
            floatx4 x1a = *(const floatx4*)(x1p + i * 8);
            floatx4 x1b = *(const floatx4*)(x1p + i * 8 + 4);
            floatx4 wa  = *(const floatx4*)(wtl + i * 8);
            floatx4 wb  = *(const floatx4*)(wtl + i * 8 + 4);
            floatx4 x2a = { __uint_as_float(u4.x << 16), __uint_as_float(u4.x & 0xffff0000u),
                            __uint_as_float(u4.y << 16), __uint_as_float(u4.y & 0xffff0000u) };
            floatx4 x2b = { __uint_as_float(u4.z << 16), __uint_as_float(u4.z & 0xffff0000u),
                            __uint_as_float(u4.w << 16), __uint_as_float(u4.w & 0xffff0000u) };
            floatx4 za = x1a + x2a;
            floatx4 zb = x1b + x2b;
            floatx4 ea = { __builtin_amdgcn_exp2f(za[0]), __builtin_amdgcn_exp2f(za[1]),
                           __builtin_amdgcn_exp2f(za[2]), __builtin_amdgcn_exp2f(za[3]) };
            floatx4 eb = { __builtin_amdgcn_exp2f(zb[0]), __builtin_amdgcn_exp2f(zb[1]),
                           __builtin_amdgcn_exp2f(zb[2]), __builtin_amdgcn_exp2f(zb[3]) };
            ea = ea + 1.f;
            eb = eb + 1.f;
            floatx4 ra = { __builtin_amdgcn_rcpf(ea[0]), __builtin_amdgcn_rcpf(ea[1]),
                           __builtin_amdgcn_rcpf(ea[2]), __builtin_amdgcn_rcpf(ea[3]) };
            floatx4 rb = { __builtin_amdgcn_rcpf(eb[0]), __builtin_amdgcn_rcpf(eb[1]),
                           __builtin_amdgcn_rcpf(eb[2]), __builtin_amdgcn_rcpf(eb[3]) };
            acc4a = acc4a + wa * ra;
            acc4b = acc4b + wb * rb;
        }
    }

    part[t] = (acc4a[0] + acc4a[1]) + (acc4a[2] + acc4a[3])
            + (acc4b[0] + acc4b[1]) + (acc4b[2] + acc4b[3]);
    __syncthreads();

    if (t < 128) {
        const float sum4 = part[t] + part[t + 128] + part[t + 256] + part[t + 384];
        const int s2 = t & 31, vi2 = t >> 5;
        const int v2 = v0 + vi2;
        const float pm2 = vmask[b * TV + v2] * smask[b * TS + s2];
        // sum4 = 4x true sum; out = pm*(wsum - 2*(0.25*sum4)) = pm*(wsum - 0.5*sum4)
        out[((size_t)b * TV + v2) * TS + s2] = pm2 * (wsum[0] - 0.5f * sum4);
    }
}

// ---------------------------------------------------------------------------
extern "C" void kernel_launch(void* const* d_in, const int* in_sizes, int n_in,
                              void* d_out, int out_size, void* d_ws, size_t ws_size,
                              hipStream_t stream)
{
    const float* video = (const float*)d_in[0];
    const float* vmask = (const float*)d_in[1];
    const float* sent  = (const float*)d_in[2];
    const float* smask = (const float*)d_in[3];
    const float* w1    = (const float*)d_in[4];
    const float* b1    = (const float*)d_in[5];
    const float* w2    = (const float*)d_in[6];
    const float* wt    = (const float*)d_in[7];
    float* out = (float*)d_out;

    const size_t NV = (size_t)BB * TV * DD, NS = (size_t)BB * TS * DD, NW = (size_t)DD * DD;

    float* tmp1          = (float*)d_ws;                  // 8 MB f32 (prescaled)
    unsigned short* tmp2 = (unsigned short*)(tmp1 + NV);  // 512 KB bf16 (prescaled)
    unsigned short* vb   = tmp2 + NS;
    unsigned short* sb   = vb + NV;
    unsigned short* w1b  = sb + NS;
    unsigned short* w2b  = w1b + NW;
    float* wsum          = (float*)(w2b + NW);

    const int total8 = (int)((NV + NS + 2 * NW) / 8);
    ta_convert<<<dim3(total8 / 256), dim3(256), 0, stream>>>(
        video, sent, w1, w2, vb, sb, w1b, w2b);
    ta_mfma_gemm<<<dim3(512 + 64), dim3(256), 0, stream>>>(
        vb, w1b, b1, vmask, tmp1, sb, w2b, smask, tmp2, wt, wsum);
    ta_tanh_main<<<dim3(BB * (TV / 4)), dim3(512), 0, stream>>>(
        tmp1, tmp2, wt, wsum, vmask, smask, out);
}

// Round 9
// 37.046 us; speedup vs baseline: 2.1076x; 2.1076x over previous
//
#include <hip/hip_runtime.h>

#define BB 16
#define TV 256
#define TS 32
#define DD 512

typedef float    floatx4  __attribute__((ext_vector_type(4)));
typedef short    short8   __attribute__((ext_vector_type(8)));
typedef unsigned short ushort8 __attribute__((ext_vector_type(8)));

#define TANH_SCALE 2.885390082f   // 2*log2(e): tanh(y)=1-2/(exp2(2y*log2e)+1)

static __device__ __forceinline__ unsigned short f2bf(float f) {
    unsigned int u = __float_as_uint(f);
    u += 0x7FFFu + ((u >> 16) & 1u);   // RNE (inputs finite)
    return (unsigned short)(u >> 16);
}

// ---------------------------------------------------------------------------
// Pass 1: convert video/sent/w1/w2 f32 -> bf16 once (memory-bound, ~26 MB).
// ---------------------------------------------------------------------------
__global__ __launch_bounds__(256) void ta_convert(
    const float* __restrict__ video, const float* __restrict__ sent,
    const float* __restrict__ w1,    const float* __restrict__ w2,
    unsigned short* __restrict__ vb, unsigned short* __restrict__ sb,
    unsigned short* __restrict__ w1b, unsigned short* __restrict__ w2b)
{
    const int NV = BB * TV * DD, NS = BB * TS * DD, NW = DD * DD;
    const int base = (blockIdx.x * 256 + threadIdx.x) * 8;
    const float* src; unsigned short* dst; int off;
    if      (base < NV)           { src = video; dst = vb;  off = base; }
    else if (base < NV + NS)      { src = sent;  dst = sb;  off = base - NV; }
    else if (base < NV + NS + NW) { src = w1;    dst = w1b; off = base - NV - NS; }
    else                          { src = w2;    dst = w2b; off = base - NV - NS - NW; }
    const float4 a = *(const float4*)(src + off);
    const float4 b = *(const float4*)(src + off + 4);
    ushort8 o;
    o[0] = f2bf(a.x); o[1] = f2bf(a.y); o[2] = f2bf(a.z); o[3] = f2bf(a.w);
    o[4] = f2bf(b.x); o[5] = f2bf(b.y); o[6] = f2bf(b.z); o[7] = f2bf(b.w);
    *(ushort8*)(dst + off) = o;
}

// ---------------------------------------------------------------------------
// Pass 2: merged bf16-MFMA NT GEMM (measured ~2.5us). NEW epilogues:
// g1: tmp1e[m][n] = exp2((val + b1[n]) * vmask[m] * C)        (E1, f32)
// g2: tmp2e[b][n][m&31] = exp2(val * smask[m] * C), TRANSPOSED (E2, f32)
// Factorization exp2(z1+z2) = E1*E2 is exact for binary masks (the final
// out is multiplied by pm, so masked pairs are zeroed regardless).
// ---------------------------------------------------------------------------
__global__ __launch_bounds__(256) void ta_mfma_gemm(
    const unsigned short* __restrict__ vb, const unsigned short* __restrict__ w1b,
    const float* __restrict__ b1,          const float* __restrict__ vmask,
    float* __restrict__ tmp1e,
    const unsigned short* __restrict__ sb, const unsigned short* __restrict__ w2b,
    const float* __restrict__ smask,       float* __restrict__ tmp2e,
    const float* __restrict__ wt,          float* __restrict__ wsum)
{
    const int t = threadIdx.x;

    if (blockIdx.x == 0 && t < 64) {
        float v = 0.f;
        for (int i = t; i < DD; i += 64) v += wt[i];
        for (int off = 32; off; off >>= 1) v += __shfl_down(v, off);
        if (t == 0) wsum[0] = v;
    }

    const bool g2 = (blockIdx.x >= 512);
    const int bid = g2 ? (int)blockIdx.x - 512 : (int)blockIdx.x;
    const unsigned short* __restrict__ A = g2 ? sb    : vb;
    const unsigned short* __restrict__ W = g2 ? w2b   : w1b;
    const float* __restrict__ rm         = g2 ? smask : vmask;
    const int m0 = (g2 ? (bid & 7)  : (bid & 63)) * 64;
    const int n0 = (g2 ? (bid >> 3) : (bid >> 6)) * 64;

    __shared__ unsigned short As[2][4096];
    __shared__ unsigned short Bs[2][4096];

    const int lane = t & 63;
    const int wid  = t >> 6;
    const int wm   = wid >> 1, wn = wid & 1;
    const int lr   = lane & 15, kg = lane >> 4;

    const int r0 = t >> 3,          g0c = (t & 7) ^ (r0 & 7);
    const int r1 = (t + 256) >> 3,  g1c = (t & 7) ^ (r1 & 7);
    const unsigned short* a0p = A + (size_t)(m0 + r0) * DD + g0c * 8;
    const unsigned short* a1p = A + (size_t)(m0 + r1) * DD + g1c * 8;
    const unsigned short* w0p = W + (size_t)(n0 + r0) * DD + g0c * 8;
    const unsigned short* w1p = W + (size_t)(n0 + r1) * DD + g1c * 8;
    const int l0 = t * 8;
    const int l1 = (t + 256) * 8;

#define TA_STAGE(buf, koff) do {                                               \
    __builtin_amdgcn_global_load_lds(                                          \
        (const __attribute__((address_space(1))) void*)(a0p + (koff)),         \
        (__attribute__((address_space(3))) void*)&As[buf][l0], 16, 0, 0);      \
    __builtin_amdgcn_global_load_lds(                                          \
        (const __attribute__((address_space(1))) void*)(a1p + (koff)),         \
        (__attribute__((address_space(3))) void*)&As[buf][l1], 16, 0, 0);      \
    __builtin_amdgcn_global_load_lds(                                          \
        (const __attribute__((address_space(1))) void*)(w0p + (koff)),         \
        (__attribute__((address_space(3))) void*)&Bs[buf][l0], 16, 0, 0);      \
    __builtin_amdgcn_global_load_lds(                                          \
        (const __attribute__((address_space(1))) void*)(w1p + (koff)),         \
        (__attribute__((address_space(3))) void*)&Bs[buf][l1], 16, 0, 0);      \
  } while (0)

    floatx4 acc[2][2] = {};

    const int ml0 = wm * 32 + lr, ml1 = ml0 + 16;
    const int nl0 = wn * 32 + lr, nl1 = nl0 + 16;
    const int sa0 = ml0 * 64, sa1 = ml1 * 64;
    const int sb0 = nl0 * 64, sb1 = nl1 * 64;
    const int xa = ml0 & 7, xb = nl0 & 7;

    TA_STAGE(0, 0);
    __syncthreads();

    int cur = 0;
    for (int step = 0; step < 8; ++step) {
        if (step < 7) TA_STAGE(cur ^ 1, (step + 1) * 64);
#pragma unroll
        for (int kk = 0; kk < 2; ++kk) {
            const int kc = kk * 4 + kg;
            short8 a0 = *(const short8*)&As[cur][sa0 + ((kc ^ xa) << 3)];
            short8 a1 = *(const short8*)&As[cur][sa1 + ((kc ^ xa) << 3)];
            short8 b0 = *(const short8*)&Bs[cur][sb0 + ((kc ^ xb) << 3)];
            short8 b1 = *(const short8*)&Bs[cur][sb1 + ((kc ^ xb) << 3)];
            acc[0][0] = __builtin_amdgcn_mfma_f32_16x16x32_bf16(a0, b0, acc[0][0], 0, 0, 0);
            acc[0][1] = __builtin_amdgcn_mfma_f32_16x16x32_bf16(a0, b1, acc[0][1], 0, 0, 0);
            acc[1][0] = __builtin_amdgcn_mfma_f32_16x16x32_bf16(a1, b0, acc[1][0], 0, 0, 0);
            acc[1][1] = __builtin_amdgcn_mfma_f32_16x16x32_bf16(a1, b1, acc[1][1], 0, 0, 0);
        }
        __syncthreads();
        cur ^= 1;
    }
#undef TA_STAGE

    // epilogue: C row = kg*4 + reg, col = lr; store exp2(prescaled)
#pragma unroll
    for (int fm = 0; fm < 2; ++fm)
#pragma unroll
        for (int fn = 0; fn < 2; ++fn)
#pragma unroll
            for (int r = 0; r < 4; ++r) {
                const int m = m0 + wm * 32 + fm * 16 + kg * 4 + r;
                const int n = n0 + wn * 32 + fn * 16 + lr;
                const float mk = rm[m] * TANH_SCALE;
                const float val = acc[fm][fn][r];
                if (!g2) {
                    tmp1e[(size_t)m * DD + n] =
                        __builtin_amdgcn_exp2f((val + b1[n]) * mk);
                } else {
                    // transposed: tmp2e[b][d][s], b = m>>5, d = n, s = m&31
                    tmp2e[(size_t)(m >> 5) * DD * TS + (size_t)n * TS + (m & 31)] =
                        __builtin_amdgcn_exp2f(val * mk);
                }
            }
}

// ---------------------------------------------------------------------------
// Pass 3: pairwise reduction with factored exponentials — 1 trans/elem.
//   term = wt / (E1[v][d]*E2[s][d] + 1);  out = pm*(wsum - 2*sum_d term)
// Block = 512 thr = 4 v x 32 s x 4 q; grid = 1024 (2 blocks/CU, 74KB LDS).
// LDS: E2-tile [d][s] f32 (lane=s -> consecutive banks, conflict-free),
// E1 4 rows [vi][d] (broadcast reads). wt read from global (L2, broadcast).
// ---------------------------------------------------------------------------
__global__ __launch_bounds__(512) void ta_tanh_main(
    const float* __restrict__ tmp1e,  // [B*TV][D] f32 = E1
    const float* __restrict__ tmp2e,  // [B][D][TS] f32 = E2 (transposed)
    const float* __restrict__ wt,     // [D]
    const float* __restrict__ wsum,   // [1]
    const float* __restrict__ vmask,  // [B*TV]
    const float* __restrict__ smask,  // [B*TS]
    float* __restrict__ out)          // [B][TV][TS]
{
    __shared__ float t2s[DD * TS];    // 64 KB  [d][s]
    __shared__ float e1s[4 * DD];     // 8 KB   [vi][d]
    __shared__ float part[512];       // 2 KB

    const int t  = threadIdx.x;
    const int b  = blockIdx.x >> 6;
    const int v0 = (blockIdx.x & 63) << 2;

    {
        const float4* src = (const float4*)(tmp2e + (size_t)b * DD * TS);
        float4* dst = (float4*)t2s;
#pragma unroll
        for (int i = 0; i < 8; ++i) dst[t + 512 * i] = src[t + 512 * i];
        const int c = t * 4, row = c >> 9, col = c & 511;
        *(float4*)&e1s[c] =
            *(const float4*)&tmp1e[(size_t)(b * TV + v0 + row) * DD + col];
    }
    __syncthreads();

    const int s  = t & 31;
    const int vi = (t >> 5) & 3;
    const int q  = __builtin_amdgcn_readfirstlane(t >> 7);

    const float* __restrict__ e1p = e1s + vi * DD + q * 128;
    const float* __restrict__ wtp = wt + q * 128;
    const int tbase = q * 4096 + s;   // t2s index: d*32+s, d = q*128+...

    floatx4 acc4a = {0.f, 0.f, 0.f, 0.f};
    floatx4 acc4b = {0.f, 0.f, 0.f, 0.f};
#pragma unroll 2
    for (int i = 0; i < 16; ++i) {
        floatx4 e1a = *(const floatx4*)(e1p + i * 8);
        floatx4 e1b = *(const floatx4*)(e1p + i * 8 + 4);
        floatx4 wa  = *(const floatx4*)(wtp + i * 8);
        floatx4 wb  = *(const floatx4*)(wtp + i * 8 + 4);
        const int dof = tbase + i * 256;
        float e20 = t2s[dof];        float e21 = t2s[dof + 32];
        float e22 = t2s[dof + 64];   float e23 = t2s[dof + 96];
        float e24 = t2s[dof + 128];  float e25 = t2s[dof + 160];
        float e26 = t2s[dof + 192];  float e27 = t2s[dof + 224];
        floatx4 da = { e1a[0] * e20 + 1.f, e1a[1] * e21 + 1.f,
                       e1a[2] * e22 + 1.f, e1a[3] * e23 + 1.f };
        floatx4 db = { e1b[0] * e24 + 1.f, e1b[1] * e25 + 1.f,
                       e1b[2] * e26 + 1.f, e1b[3] * e27 + 1.f };
        floatx4 ra = { __builtin_amdgcn_rcpf(da[0]), __builtin_amdgcn_rcpf(da[1]),
                       __builtin_amdgcn_rcpf(da[2]), __builtin_amdgcn_rcpf(da[3]) };
        floatx4 rb = { __builtin_amdgcn_rcpf(db[0]), __builtin_amdgcn_rcpf(db[1]),
                       __builtin_amdgcn_rcpf(db[2]), __builtin_amdgcn_rcpf(db[3]) };
        acc4a = acc4a + wa * ra;
        acc4b = acc4b + wb * rb;
    }

    part[t] = (acc4a[0] + acc4a[1]) + (acc4a[2] + acc4a[3])
            + (acc4b[0] + acc4b[1]) + (acc4b[2] + acc4b[3]);
    __syncthreads();

    if (t < 128) {
        const float sum = part[t] + part[t + 128] + part[t + 256] + part[t + 384];
        const int s2 = t & 31, vi2 = t >> 5;
        const int v2 = v0 + vi2;
        const float pm2 = vmask[b * TV + v2] * smask[b * TS + s2];
        out[((size_t)b * TV + v2) * TS + s2] = pm2 * (wsum[0] - 2.f * sum);
    }
}

// ---------------------------------------------------------------------------
extern "C" void kernel_launch(void* const* d_in, const int* in_sizes, int n_in,
                              void* d_out, int out_size, void* d_ws, size_t ws_size,
                              hipStream_t stream)
{
    const float* video = (const float*)d_in[0];
    const float* vmask = (const float*)d_in[1];
    const float* sent  = (const float*)d_in[2];
    const float* smask = (const float*)d_in[3];
    const float* w1    = (const float*)d_in[4];
    const float* b1    = (const float*)d_in[5];
    const float* w2    = (const float*)d_in[6];
    const float* wt    = (const float*)d_in[7];
    float* out = (float*)d_out;

    const size_t NV = (size_t)BB * TV * DD, NS = (size_t)BB * TS * DD, NW = (size_t)DD * DD;

    float* tmp1e         = (float*)d_ws;                  // 8 MB f32 (E1)
    float* tmp2e         = tmp1e + NV;                    // 1 MB f32 (E2, transposed)
    unsigned short* vb   = (unsigned short*)(tmp2e + NS); // 4 MB
    unsigned short* sb   = vb + NV;                       // 512 KB
    unsigned short* w1b  = sb + NS;                       // 512 KB
    unsigned short* w2b  = w1b + NW;                      // 512 KB
    float* wsum          = (float*)(w2b + NW);            // 4 B

    const int total8 = (int)((NV + NS + 2 * NW) / 8);
    ta_convert<<<dim3(total8 / 256), dim3(256), 0, stream>>>(
        video, sent, w1, w2, vb, sb, w1b, w2b);
    ta_mfma_gemm<<<dim3(512 + 64), dim3(256), 0, stream>>>(
        vb, w1b, b1, vmask, tmp1e, sb, w2b, smask, tmp2e, wt, wsum);
    ta_tanh_main<<<dim3(BB * (TV / 4)), dim3(512), 0, stream>>>(
        tmp1e, tmp2e, wt, wsum, vmask, smask, out);
}

// Round 10
// 36.444 us; speedup vs baseline: 2.1425x; 1.0165x over previous
//
#include <hip/hip_runtime.h>

#define BB 16
#define TV 256
#define TS 32
#define DD 512

typedef float    floatx4  __attribute__((ext_vector_type(4)));
typedef short    short8   __attribute__((ext_vector_type(8)));
typedef unsigned short ushort8 __attribute__((ext_vector_type(8)));

#define TANH_SCALE 2.885390082f   // 2*log2(e): tanh(y)=1-2/(exp2(2y*log2e)+1)

static __device__ __forceinline__ unsigned short f2bf(float f) {
    unsigned int u = __float_as_uint(f);
    u += 0x7FFFu + ((u >> 16) & 1u);   // RNE (inputs finite)
    return (unsigned short)(u >> 16);
}

// ---------------------------------------------------------------------------
// Pass 1: convert video/sent/w1/w2 f32 -> bf16 once (memory-bound, ~17 MB).
// ---------------------------------------------------------------------------
__global__ __launch_bounds__(256) void ta_convert(
    const float* __restrict__ video, const float* __restrict__ sent,
    const float* __restrict__ w1,    const float* __restrict__ w2,
    unsigned short* __restrict__ vb, unsigned short* __restrict__ sb,
    unsigned short* __restrict__ w1b, unsigned short* __restrict__ w2b)
{
    const int NV = BB * TV * DD, NS = BB * TS * DD, NW = DD * DD;
    const int base = (blockIdx.x * 256 + threadIdx.x) * 8;
    const float* src; unsigned short* dst; int off;
    if      (base < NV)           { src = video; dst = vb;  off = base; }
    else if (base < NV + NS)      { src = sent;  dst = sb;  off = base - NV; }
    else if (base < NV + NS + NW) { src = w1;    dst = w1b; off = base - NV - NS; }
    else                          { src = w2;    dst = w2b; off = base - NV - NS - NW; }
    const float4 a = *(const float4*)(src + off);
    const float4 b = *(const float4*)(src + off + 4);
    ushort8 o;
    o[0] = f2bf(a.x); o[1] = f2bf(a.y); o[2] = f2bf(a.z); o[3] = f2bf(a.w);
    o[4] = f2bf(b.x); o[5] = f2bf(b.y); o[6] = f2bf(b.z); o[7] = f2bf(b.w);
    *(ushort8*)(dst + off) = o;
}

// ---------------------------------------------------------------------------
// Pass 2: merged bf16-MFMA NT GEMM (~2.5us). Epilogues store FACTORED exps,
// z clamped to +-30 (10 sigma; tanh saturated -> exact, and keeps all pair
// products finite for the consumer's paired-rcp trick):
// g1: tmp1e[m][n] = exp2(clamp((val+b1[n])*vmask[m]*C))          f32
// g2: tmp2h bf16, layout [b][n>>1][s][2]  (s = m&31)             bf16
// ---------------------------------------------------------------------------
__global__ __launch_bounds__(256) void ta_mfma_gemm(
    const unsigned short* __restrict__ vb, const unsigned short* __restrict__ w1b,
    const float* __restrict__ b1,          const float* __restrict__ vmask,
    float* __restrict__ tmp1e,
    const unsigned short* __restrict__ sb, const unsigned short* __restrict__ w2b,
    const float* __restrict__ smask,       unsigned short* __restrict__ tmp2h,
    const float* __restrict__ wt,          float* __restrict__ wsum)
{
    const int t = threadIdx.x;

    if (blockIdx.x == 0 && t < 64) {
        float v = 0.f;
        for (int i = t; i < DD; i += 64) v += wt[i];
        for (int off = 32; off; off >>= 1) v += __shfl_down(v, off);
        if (t == 0) wsum[0] = v;
    }

    const bool g2 = (blockIdx.x >= 512);
    const int bid = g2 ? (int)blockIdx.x - 512 : (int)blockIdx.x;
    const unsigned short* __restrict__ A = g2 ? sb    : vb;
    const unsigned short* __restrict__ W = g2 ? w2b   : w1b;
    const float* __restrict__ rm         = g2 ? smask : vmask;
    const int m0 = (g2 ? (bid & 7)  : (bid & 63)) * 64;
    const int n0 = (g2 ? (bid >> 3) : (bid >> 6)) * 64;

    __shared__ unsigned short As[2][4096];
    __shared__ unsigned short Bs[2][4096];

    const int lane = t & 63;
    const int wid  = t >> 6;
    const int wm   = wid >> 1, wn = wid & 1;
    const int lr   = lane & 15, kg = lane >> 4;

    const int r0 = t >> 3,          g0c = (t & 7) ^ (r0 & 7);
    const int r1 = (t + 256) >> 3,  g1c = (t & 7) ^ (r1 & 7);
    const unsigned short* a0p = A + (size_t)(m0 + r0) * DD + g0c * 8;
    const unsigned short* a1p = A + (size_t)(m0 + r1) * DD + g1c * 8;
    const unsigned short* w0p = W + (size_t)(n0 + r0) * DD + g0c * 8;
    const unsigned short* w1p = W + (size_t)(n0 + r1) * DD + g1c * 8;
    const int l0 = t * 8;
    const int l1 = (t + 256) * 8;

#define TA_STAGE(buf, koff) do {                                               \
    __builtin_amdgcn_global_load_lds(                                          \
        (const __attribute__((address_space(1))) void*)(a0p + (koff)),         \
        (__attribute__((address_space(3))) void*)&As[buf][l0], 16, 0, 0);      \
    __builtin_amdgcn_global_load_lds(                                          \
        (const __attribute__((address_space(1))) void*)(a1p + (koff)),         \
        (__attribute__((address_space(3))) void*)&As[buf][l1], 16, 0, 0);      \
    __builtin_amdgcn_global_load_lds(                                          \
        (const __attribute__((address_space(1))) void*)(w0p + (koff)),         \
        (__attribute__((address_space(3))) void*)&Bs[buf][l0], 16, 0, 0);      \
    __builtin_amdgcn_global_load_lds(                                          \
        (const __attribute__((address_space(1))) void*)(w1p + (koff)),         \
        (__attribute__((address_space(3))) void*)&Bs[buf][l1], 16, 0, 0);      \
  } while (0)

    floatx4 acc[2][2] = {};

    const int ml0 = wm * 32 + lr, ml1 = ml0 + 16;
    const int nl0 = wn * 32 + lr, nl1 = nl0 + 16;
    const int sa0 = ml0 * 64, sa1 = ml1 * 64;
    const int sb0 = nl0 * 64, sb1 = nl1 * 64;
    const int xa = ml0 & 7, xb = nl0 & 7;

    TA_STAGE(0, 0);
    __syncthreads();

    int cur = 0;
    for (int step = 0; step < 8; ++step) {
        if (step < 7) TA_STAGE(cur ^ 1, (step + 1) * 64);
#pragma unroll
        for (int kk = 0; kk < 2; ++kk) {
            const int kc = kk * 4 + kg;
            short8 a0 = *(const short8*)&As[cur][sa0 + ((kc ^ xa) << 3)];
            short8 a1 = *(const short8*)&As[cur][sa1 + ((kc ^ xa) << 3)];
            short8 b0 = *(const short8*)&Bs[cur][sb0 + ((kc ^ xb) << 3)];
            short8 b1 = *(const short8*)&Bs[cur][sb1 + ((kc ^ xb) << 3)];
            acc[0][0] = __builtin_amdgcn_mfma_f32_16x16x32_bf16(a0, b0, acc[0][0], 0, 0, 0);
            acc[0][1] = __builtin_amdgcn_mfma_f32_16x16x32_bf16(a0, b1, acc[0][1], 0, 0, 0);
            acc[1][0] = __builtin_amdgcn_mfma_f32_16x16x32_bf16(a1, b0, acc[1][0], 0, 0, 0);
            acc[1][1] = __builtin_amdgcn_mfma_f32_16x16x32_bf16(a1, b1, acc[1][1], 0, 0, 0);
        }
        __syncthreads();
        cur ^= 1;
    }
#undef TA_STAGE

    // epilogue: C row = kg*4 + reg, col = lr
#pragma unroll
    for (int fm = 0; fm < 2; ++fm)
#pragma unroll
        for (int fn = 0; fn < 2; ++fn)
#pragma unroll
            for (int r = 0; r < 4; ++r) {
                const int m = m0 + wm * 32 + fm * 16 + kg * 4 + r;
                const int n = n0 + wn * 32 + fn * 16 + lr;
                const float mk = rm[m] * TANH_SCALE;
                float z = g2 ? (acc[fm][fn][r] * mk)
                             : (acc[fm][fn][r] + b1[n]) * mk;
                z = fminf(fmaxf(z, -30.f), 30.f);
                const float e = __builtin_amdgcn_exp2f(z);
                if (!g2) {
                    tmp1e[(size_t)m * DD + n] = e;
                } else {
                    // [b][n>>1][s][2] bf16 pairs
                    tmp2h[(size_t)(m >> 5) * 16384 + (size_t)(n >> 1) * 64
                          + (m & 31) * 2 + (n & 1)] = f2bf(e);
                }
            }
}

// ---------------------------------------------------------------------------
// Pass 3: pairwise reduction, factored exps, PAIRED reciprocals.
//   term = wt / (E1*E2 + 1);  out = pm*(wsum - 2*sum_d term)
// Block = 512 thr = 32 s x 4 vi x 4 q, each thread handles 2 v (vi, vi+4)
// -> 8 v/block, grid = 512 (2 blocks/CU @ 52KB LDS).
// E2: bf16 pairs [d2][s][2] in LDS (stage = coalesced 32KB copy); reads are
// consecutive-lane uint -> conflict-free. E1: f32 8 rows (16KB), broadcast.
// Paired rcp: inv = rcp(dlo*dhi); rlo = dhi*inv; rhi = dlo*inv  (8 trans/iter).
// ---------------------------------------------------------------------------
__global__ __launch_bounds__(512, 4) void ta_tanh_main(
    const float* __restrict__ tmp1e,          // [B*TV][D] f32 = E1
    const unsigned short* __restrict__ tmp2h, // [B][D/2][TS][2] bf16 = E2
    const float* __restrict__ wt,             // [D]
    const float* __restrict__ wsum,           // [1]
    const float* __restrict__ vmask,          // [B*TV]
    const float* __restrict__ smask,          // [B*TS]
    float* __restrict__ out)                  // [B][TV][TS]
{
    __shared__ unsigned int t2u[8192];   // 32 KB: [d2][s] bf16-pairs
    __shared__ float e1s[8 * DD];        // 16 KB: [sv][d]
    __shared__ float part[1024];         // 4 KB:  [sv][s][q]

    const int t  = threadIdx.x;
    const int b  = blockIdx.x >> 5;          // 32 v-tiles (8 v) per batch
    const int v0 = (blockIdx.x & 31) << 3;

    {   // stage E2 (coalesced) + E1
        const ushort8* src = (const ushort8*)(tmp2h + (size_t)b * 16384);
        ushort8* dst = (ushort8*)t2u;
#pragma unroll
        for (int i = 0; i < 4; ++i) dst[t + 512 * i] = src[t + 512 * i];
#pragma unroll
        for (int i = 0; i < 2; ++i) {
            const int c = t + 512 * i;       // 0..1023 float4 chunks
            const int row = c >> 7, col = (c & 127) << 2;
            *(float4*)&e1s[row * DD + col] =
                *(const float4*)&tmp1e[(size_t)(b * TV + v0 + row) * DD + col];
        }
    }
    __syncthreads();

    const int s  = t & 31;
    const int vi = (t >> 5) & 3;
    const int q  = t >> 7;                   // wave-uniform

    const float* __restrict__ e1lo = e1s + vi * DD + q * 128;
    const float* __restrict__ e1hi = e1s + (vi + 4) * DD + q * 128;
    const float* __restrict__ wtp  = wt + q * 128;
    const int ubase = q * 2048 + s;          // uint idx = d2*32 + s

    floatx4 alo = {0.f, 0.f, 0.f, 0.f};
    floatx4 ahi = {0.f, 0.f, 0.f, 0.f};
#pragma unroll 4
    for (int i = 0; i < 16; ++i) {
        const int ub = ubase + i * 128;
        const unsigned u0 = t2u[ub];
        const unsigned u1 = t2u[ub + 32];
        const unsigned u2 = t2u[ub + 64];
        const unsigned u3 = t2u[ub + 96];
        floatx4 xl0 = *(const floatx4*)(e1lo + i * 8);
        floatx4 xl1 = *(const floatx4*)(e1lo + i * 8 + 4);
        floatx4 xh0 = *(const floatx4*)(e1hi + i * 8);
        floatx4 xh1 = *(const floatx4*)(e1hi + i * 8 + 4);
        floatx4 wa  = *(const floatx4*)(wtp + i * 8);
        floatx4 wb  = *(const floatx4*)(wtp + i * 8 + 4);
        float e2[8] = {
            __uint_as_float(u0 << 16), __uint_as_float(u0 & 0xffff0000u),
            __uint_as_float(u1 << 16), __uint_as_float(u1 & 0xffff0000u),
            __uint_as_float(u2 << 16), __uint_as_float(u2 & 0xffff0000u),
            __uint_as_float(u3 << 16), __uint_as_float(u3 & 0xffff0000u)
        };
#pragma unroll
        for (int j = 0; j < 4; ++j) {
            const float dlo = fmaf(xl0[j], e2[j], 1.f);
            const float dhi = fmaf(xh0[j], e2[j], 1.f);
            const float inv = __builtin_amdgcn_rcpf(dlo * dhi);
            alo[j] = fmaf(wa[j], dhi * inv, alo[j]);
            ahi[j] = fmaf(wa[j], dlo * inv, ahi[j]);
        }
#pragma unroll
        for (int j = 0; j < 4; ++j) {
            const float dlo = fmaf(xl1[j], e2[j + 4], 1.f);
            const float dhi = fmaf(xh1[j], e2[j + 4], 1.f);
            const float inv = __builtin_amdgcn_rcpf(dlo * dhi);
            alo[j] = fmaf(wb[j], dhi * inv, alo[j]);
            ahi[j] = fmaf(wb[j], dlo * inv, ahi[j]);
        }
    }

    part[vi * 128 + s * 4 + q]       = (alo[0] + alo[1]) + (alo[2] + alo[3]);
    part[(vi + 4) * 128 + s * 4 + q] = (ahi[0] + ahi[1]) + (ahi[2] + ahi[3]);
    __syncthreads();

    if (t < 256) {
        const int sv = t >> 5, s2 = t & 31;
        const float4 p4 = *(const float4*)&part[sv * 128 + s2 * 4];
        const float sum = (p4.x + p4.y) + (p4.z + p4.w);
        const int v = v0 + sv;
        const float pm = vmask[b * TV + v] * smask[b * TS + s2];
        out[((size_t)b * TV + v) * TS + s2] = pm * (wsum[0] - 2.f * sum);
    }
}

// ---------------------------------------------------------------------------
extern "C" void kernel_launch(void* const* d_in, const int* in_sizes, int n_in,
                              void* d_out, int out_size, void* d_ws, size_t ws_size,
                              hipStream_t stream)
{
    const float* video = (const float*)d_in[0];
    const float* vmask = (const float*)d_in[1];
    const float* sent  = (const float*)d_in[2];
    const float* smask = (const float*)d_in[3];
    const float* w1    = (const float*)d_in[4];
    const float* b1    = (const float*)d_in[5];
    const float* w2    = (const float*)d_in[6];
    const float* wt    = (const float*)d_in[7];
    float* out = (float*)d_out;

    const size_t NV = (size_t)BB * TV * DD, NS = (size_t)BB * TS * DD, NW = (size_t)DD * DD;

    float* tmp1e         = (float*)d_ws;                   // 8 MB f32 (E1)
    unsigned short* tmp2h = (unsigned short*)(tmp1e + NV); // 512 KB bf16 (E2 pairs)
    unsigned short* vb   = tmp2h + NS;                     // 4 MB
    unsigned short* sb   = vb + NV;                        // 512 KB
    unsigned short* w1b  = sb + NS;                        // 512 KB
    unsigned short* w2b  = w1b + NW;                       // 512 KB
    float* wsum          = (float*)(w2b + NW);             // 4 B

    const int total8 = (int)((NV + NS + 2 * NW) / 8);
    ta_convert<<<dim3(total8 / 256), dim3(256), 0, stream>>>(
        video, sent, w1, w2, vb, sb, w1b, w2b);
    ta_mfma_gemm<<<dim3(512 + 64), dim3(256), 0, stream>>>(
        vb, w1b, b1, vmask, tmp1e, sb, w2b, smask, tmp2h, wt, wsum);
    ta_tanh_main<<<dim3(BB * (TV / 8)), dim3(512), 0, stream>>>(
        tmp1e, tmp2h, wt, wsum, vmask, smask, out);
}

// Round 11
// 35.757 us; speedup vs baseline: 2.1836x; 1.0192x over previous
//
#include <hip/hip_runtime.h>

#define BB 16
#define TV 256
#define TS 32
#define DD 512

typedef float    floatx4  __attribute__((ext_vector_type(4)));
typedef short    short8   __attribute__((ext_vector_type(8)));
typedef unsigned short ushort8 __attribute__((ext_vector_type(8)));

#define TANH_SCALE 2.885390082f   // 2*log2(e): tanh(y)=1-2/(exp2(2y*log2e)+1)

static __device__ __forceinline__ unsigned short f2bf(float f) {
    unsigned int u = __float_as_uint(f);
    u += 0x7FFFu + ((u >> 16) & 1u);   // RNE (inputs finite)
    return (unsigned short)(u >> 16);
}

// ---------------------------------------------------------------------------
// Pass 1: convert video/sent/w1/w2 f32 -> bf16 once (memory-bound, ~26 MB).
// ---------------------------------------------------------------------------
__global__ __launch_bounds__(256) void ta_convert(
    const float* __restrict__ video, const float* __restrict__ sent,
    const float* __restrict__ w1,    const float* __restrict__ w2,
    unsigned short* __restrict__ vb, unsigned short* __restrict__ sb,
    unsigned short* __restrict__ w1b, unsigned short* __restrict__ w2b)
{
    const int NV = BB * TV * DD, NS = BB * TS * DD, NW = DD * DD;
    const int base = (blockIdx.x * 256 + threadIdx.x) * 8;
    const float* src; unsigned short* dst; int off;
    if      (base < NV)           { src = video; dst = vb;  off = base; }
    else if (base < NV + NS)      { src = sent;  dst = sb;  off = base - NV; }
    else if (base < NV + NS + NW) { src = w1;    dst = w1b; off = base - NV - NS; }
    else                          { src = w2;    dst = w2b; off = base - NV - NS - NW; }
    const float4 a = *(const float4*)(src + off);
    const float4 b = *(const float4*)(src + off + 4);
    ushort8 o;
    o[0] = f2bf(a.x); o[1] = f2bf(a.y); o[2] = f2bf(a.z); o[3] = f2bf(a.w);
    o[4] = f2bf(b.x); o[5] = f2bf(b.y); o[6] = f2bf(b.z); o[7] = f2bf(b.w);
    *(ushort8*)(dst + off) = o;
}

// ---------------------------------------------------------------------------
// Pass 2: merged bf16-MFMA NT GEMM (~2.5us). Epilogues store FACTORED exps
// as bf16, z clamped to +-30 (tanh saturated -> exact):
// g1: tmp1h[m][n]  = bf16(exp2(clamp((val+b1[n])*vmask[m]*C)))
// g2: tmp2h, layout [b][s>>4][n>>1][s&15][n&1] bf16  (s-half-split for the
//     consumer's 16KB LDS tile; staging becomes one contiguous copy)
// ---------------------------------------------------------------------------
__global__ __launch_bounds__(256) void ta_mfma_gemm(
    const unsigned short* __restrict__ vb, const unsigned short* __restrict__ w1b,
    const float* __restrict__ b1,          const float* __restrict__ vmask,
    unsigned short* __restrict__ tmp1h,
    const unsigned short* __restrict__ sb, const unsigned short* __restrict__ w2b,
    const float* __restrict__ smask,       unsigned short* __restrict__ tmp2h,
    const float* __restrict__ wt,          float* __restrict__ wsum)
{
    const int t = threadIdx.x;

    if (blockIdx.x == 0 && t < 64) {
        float v = 0.f;
        for (int i = t; i < DD; i += 64) v += wt[i];
        for (int off = 32; off; off >>= 1) v += __shfl_down(v, off);
        if (t == 0) wsum[0] = v;
    }

    const bool g2 = (blockIdx.x >= 512);
    const int bid = g2 ? (int)blockIdx.x - 512 : (int)blockIdx.x;
    const unsigned short* __restrict__ A = g2 ? sb    : vb;
    const unsigned short* __restrict__ W = g2 ? w2b   : w1b;
    const float* __restrict__ rm         = g2 ? smask : vmask;
    const int m0 = (g2 ? (bid & 7)  : (bid & 63)) * 64;
    const int n0 = (g2 ? (bid >> 3) : (bid >> 6)) * 64;

    __shared__ unsigned short As[2][4096];
    __shared__ unsigned short Bs[2][4096];

    const int lane = t & 63;
    const int wid  = t >> 6;
    const int wm   = wid >> 1, wn = wid & 1;
    const int lr   = lane & 15, kg = lane >> 4;

    const int r0 = t >> 3,          g0c = (t & 7) ^ (r0 & 7);
    const int r1 = (t + 256) >> 3,  g1c = (t & 7) ^ (r1 & 7);
    const unsigned short* a0p = A + (size_t)(m0 + r0) * DD + g0c * 8;
    const unsigned short* a1p = A + (size_t)(m0 + r1) * DD + g1c * 8;
    const unsigned short* w0p = W + (size_t)(n0 + r0) * DD + g0c * 8;
    const unsigned short* w1p = W + (size_t)(n0 + r1) * DD + g1c * 8;
    const int l0 = t * 8;
    const int l1 = (t + 256) * 8;

#define TA_STAGE(buf, koff) do {                                               \
    __builtin_amdgcn_global_load_lds(                                          \
        (const __attribute__((address_space(1))) void*)(a0p + (koff)),         \
        (__attribute__((address_space(3))) void*)&As[buf][l0], 16, 0, 0);      \
    __builtin_amdgcn_global_load_lds(                                          \
        (const __attribute__((address_space(1))) void*)(a1p + (koff)),         \
        (__attribute__((address_space(3))) void*)&As[buf][l1], 16, 0, 0);      \
    __builtin_amdgcn_global_load_lds(                                          \
        (const __attribute__((address_space(1))) void*)(w0p + (koff)),         \
        (__attribute__((address_space(3))) void*)&Bs[buf][l0], 16, 0, 0);      \
    __builtin_amdgcn_global_load_lds(                                          \
        (const __attribute__((address_space(1))) void*)(w1p + (koff)),         \
        (__attribute__((address_space(3))) void*)&Bs[buf][l1], 16, 0, 0);      \
  } while (0)

    floatx4 acc[2][2] = {};

    const int ml0 = wm * 32 + lr, ml1 = ml0 + 16;
    const int nl0 = wn * 32 + lr, nl1 = nl0 + 16;
    const int sa0 = ml0 * 64, sa1 = ml1 * 64;
    const int sb0 = nl0 * 64, sb1 = nl1 * 64;
    const int xa = ml0 & 7, xb = nl0 & 7;

    TA_STAGE(0, 0);
    __syncthreads();

    int cur = 0;
    for (int step = 0; step < 8; ++step) {
        if (step < 7) TA_STAGE(cur ^ 1, (step + 1) * 64);
#pragma unroll
        for (int kk = 0; kk < 2; ++kk) {
            const int kc = kk * 4 + kg;
            short8 a0 = *(const short8*)&As[cur][sa0 + ((kc ^ xa) << 3)];
            short8 a1 = *(const short8*)&As[cur][sa1 + ((kc ^ xa) << 3)];
            short8 b0 = *(const short8*)&Bs[cur][sb0 + ((kc ^ xb) << 3)];
            short8 b1 = *(const short8*)&Bs[cur][sb1 + ((kc ^ xb) << 3)];
            acc[0][0] = __builtin_amdgcn_mfma_f32_16x16x32_bf16(a0, b0, acc[0][0], 0, 0, 0);
            acc[0][1] = __builtin_amdgcn_mfma_f32_16x16x32_bf16(a0, b1, acc[0][1], 0, 0, 0);
            acc[1][0] = __builtin_amdgcn_mfma_f32_16x16x32_bf16(a1, b0, acc[1][0], 0, 0, 0);
            acc[1][1] = __builtin_amdgcn_mfma_f32_16x16x32_bf16(a1, b1, acc[1][1], 0, 0, 0);
        }
        __syncthreads();
        cur ^= 1;
    }
#undef TA_STAGE

    // epilogue: C row = kg*4 + reg, col = lr
#pragma unroll
    for (int fm = 0; fm < 2; ++fm)
#pragma unroll
        for (int fn = 0; fn < 2; ++fn)
#pragma unroll
            for (int r = 0; r < 4; ++r) {
                const int m = m0 + wm * 32 + fm * 16 + kg * 4 + r;
                const int n = n0 + wn * 32 + fn * 16 + lr;
                const float mk = rm[m] * TANH_SCALE;
                float z = g2 ? (acc[fm][fn][r] * mk)
                             : (acc[fm][fn][r] + b1[n]) * mk;
                z = fminf(fmaxf(z, -30.f), 30.f);
                const float e = __builtin_amdgcn_exp2f(z);
                if (!g2) {
                    tmp1h[(size_t)m * DD + n] = f2bf(e);
                } else {
                    const int bb = m >> 5, ss = m & 31;
                    tmp2h[(size_t)bb * 16384 + (size_t)(ss >> 4) * 8192
                          + (size_t)(n >> 1) * 32 + (ss & 15) * 2 + (n & 1)] = f2bf(e);
                }
            }
}

// ---------------------------------------------------------------------------
// Pass 3: pairwise reduction, factored bf16 exps, paired rcp — OCCUPANCY
// build: block 256 thr = 16 s x 2 vi x 8 q; thread handles 2 v (vi, vi+2);
// grid = B x (TV/4) x 2 s-halves = 2048 -> 8 blocks/CU @ 18KB LDS.
// E2 s-half tile (16KB) in LDS (contiguous stage); E1 read from global bf16
// (L1/L2-hot, 16-lane broadcast); wt from global (L1 broadcast).
//   term = wt / (E1*E2 + 1);  out = pm*(wsum - 2*sum_d term)
// ---------------------------------------------------------------------------
__global__ __launch_bounds__(256) void ta_tanh_main(
    const unsigned short* __restrict__ tmp1h, // [B*TV][D] bf16 = E1
    const unsigned short* __restrict__ tmp2h, // [B][2][D/2][16][2] bf16 = E2
    const float* __restrict__ wt,             // [D]
    const float* __restrict__ wsum,           // [1]
    const float* __restrict__ vmask,          // [B*TV]
    const float* __restrict__ smask,          // [B*TS]
    float* __restrict__ out)                  // [B][TV][TS]
{
    __shared__ unsigned int e2u[4096];   // 16 KB: [d2 256][s16] bf16-pairs
    __shared__ float part[512];          // 2 KB:  [4v][16s][8q]

    const int t   = threadIdx.x;
    const int bid = blockIdx.x;
    const int b   = bid >> 7;            // 16 batches
    const int vt  = (bid >> 1) & 63;     // 64 v-tiles of 4
    const int sh  = bid & 1;             // s-half
    const int v0  = vt << 2;

    {   // stage E2 s-half tile: contiguous 16 KB copy
        const ushort8* src = (const ushort8*)(tmp2h + (size_t)b * 16384 + sh * 8192);
        ushort8* dst = (ushort8*)e2u;
#pragma unroll
        for (int i = 0; i < 4; ++i) dst[t + 256 * i] = src[t + 256 * i];
    }
    __syncthreads();

    const int s  = t & 15;
    const int vi = (t >> 4) & 1;
    const int q  = t >> 5;               // 0..7, 64-d slice

    const unsigned short* __restrict__ e1lo =
        tmp1h + (size_t)(b * TV + v0 + vi) * DD + q * 64;
    const unsigned short* __restrict__ e1hi = e1lo + 2 * DD;   // v0+vi+2
    const float* __restrict__ wtp = wt + q * 64;
    const int ubase = (q * 32) * 16 + s;   // u32 idx = d2*16 + s

    floatx4 alo = {0.f, 0.f, 0.f, 0.f};
    floatx4 ahi = {0.f, 0.f, 0.f, 0.f};
#pragma unroll 2
    for (int i = 0; i < 8; ++i) {
        const int ub = ubase + i * 64;
        const unsigned u0 = e2u[ub];
        const unsigned u1 = e2u[ub + 16];
        const unsigned u2 = e2u[ub + 32];
        const unsigned u3 = e2u[ub + 48];
        ushort8 l8 = *(const ushort8*)(e1lo + i * 8);
        ushort8 h8 = *(const ushort8*)(e1hi + i * 8);
        floatx4 wa = *(const floatx4*)(wtp + i * 8);
        floatx4 wb = *(const floatx4*)(wtp + i * 8 + 4);
        const float e2v[8] = {
            __uint_as_float(u0 << 16), __uint_as_float(u0 & 0xffff0000u),
            __uint_as_float(u1 << 16), __uint_as_float(u1 & 0xffff0000u),
            __uint_as_float(u2 << 16), __uint_as_float(u2 & 0xffff0000u),
            __uint_as_float(u3 << 16), __uint_as_float(u3 & 0xffff0000u)
        };
#pragma unroll
        for (int j = 0; j < 4; ++j) {
            const float xl = __uint_as_float((unsigned)l8[j] << 16);
            const float xh = __uint_as_float((unsigned)h8[j] << 16);
            const float dlo = fmaf(xl, e2v[j], 1.f);
            const float dhi = fmaf(xh, e2v[j], 1.f);
            const float inv = __builtin_amdgcn_rcpf(dlo * dhi);
            alo[j] = fmaf(wa[j], dhi * inv, alo[j]);
            ahi[j] = fmaf(wa[j], dlo * inv, ahi[j]);
        }
#pragma unroll
        for (int j = 0; j < 4; ++j) {
            const float xl = __uint_as_float((unsigned)l8[j + 4] << 16);
            const float xh = __uint_as_float((unsigned)h8[j + 4] << 16);
            const float dlo = fmaf(xl, e2v[j + 4], 1.f);
            const float dhi = fmaf(xh, e2v[j + 4], 1.f);
            const float inv = __builtin_amdgcn_rcpf(dlo * dhi);
            alo[j] = fmaf(wb[j], dhi * inv, alo[j]);
            ahi[j] = fmaf(wb[j], dlo * inv, ahi[j]);
        }
    }

    part[(vi    ) * 128 + s * 8 + q] = (alo[0] + alo[1]) + (alo[2] + alo[3]);
    part[(vi + 2) * 128 + s * 8 + q] = (ahi[0] + ahi[1]) + (ahi[2] + ahi[3]);
    __syncthreads();

    if (t < 64) {
        const int vrow = t >> 4, s2 = t & 15;
        const floatx4 p0 = *(const floatx4*)&part[vrow * 128 + s2 * 8];
        const floatx4 p1 = *(const floatx4*)&part[vrow * 128 + s2 * 8 + 4];
        const float sum = ((p0[0] + p0[1]) + (p0[2] + p0[3]))
                        + ((p1[0] + p1[1]) + (p1[2] + p1[3]));
        const int v  = v0 + vrow;
        const int sg = sh * 16 + s2;
        const float pm = vmask[b * TV + v] * smask[b * TS + sg];
        out[((size_t)b * TV + v) * TS + sg] = pm * (wsum[0] - 2.f * sum);
    }
}

// ---------------------------------------------------------------------------
extern "C" void kernel_launch(void* const* d_in, const int* in_sizes, int n_in,
                              void* d_out, int out_size, void* d_ws, size_t ws_size,
                              hipStream_t stream)
{
    const float* video = (const float*)d_in[0];
    const float* vmask = (const float*)d_in[1];
    const float* sent  = (const float*)d_in[2];
    const float* smask = (const float*)d_in[3];
    const float* w1    = (const float*)d_in[4];
    const float* b1    = (const float*)d_in[5];
    const float* w2    = (const float*)d_in[6];
    const float* wt    = (const float*)d_in[7];
    float* out = (float*)d_out;

    const size_t NV = (size_t)BB * TV * DD, NS = (size_t)BB * TS * DD, NW = (size_t)DD * DD;

    unsigned short* tmp1h = (unsigned short*)d_ws;   // 4 MB bf16 (E1)
    unsigned short* tmp2h = tmp1h + NV;              // 512 KB bf16 (E2, s-half layout)
    unsigned short* vb    = tmp2h + NS;              // 4 MB
    unsigned short* sb    = vb + NV;                 // 512 KB
    unsigned short* w1b   = sb + NS;                 // 512 KB
    unsigned short* w2b   = w1b + NW;                // 512 KB
    float* wsum           = (float*)(w2b + NW);      // 4 B

    const int total8 = (int)((NV + NS + 2 * NW) / 8);
    ta_convert<<<dim3(total8 / 256), dim3(256), 0, stream>>>(
        video, sent, w1, w2, vb, sb, w1b, w2b);
    ta_mfma_gemm<<<dim3(512 + 64), dim3(256), 0, stream>>>(
        vb, w1b, b1, vmask, tmp1h, sb, w2b, smask, tmp2h, wt, wsum);
    ta_tanh_main<<<dim3(BB * (TV / 4) * 2), dim3(256), 0, stream>>>(
        tmp1h, tmp2h, wt, wsum, vmask, smask, out);
}